// Round 1
// baseline (1357.278 us; speedup 1.0000x reference)
//
#include <hip/hip_runtime.h>
#include <cstddef>

#define DMODEL 512
#define DINNER 1024
#define DSTATE 16
#define DTRANK 32
#define DCONV  4
#define NB     4
#define NL     1024
#define NR     (NB * NL)   // 4096 rows (b*L)

// ---------------------------------------------------------------------------
// C[M,N] = A[M,K] * Bw[N,K]^T   (row-major everywhere, fp32 VALU GEMM)
// 64x64 block tile, 256 threads, 4x4 register tile per thread, BK=16.
// Requires M%64==0, N%64==0, K%16==0.
// ---------------------------------------------------------------------------
__global__ __launch_bounds__(256) void gemm_nt_kernel(
    const float* __restrict__ A, const float* __restrict__ Bw,
    float* __restrict__ C, int M, int N, int K)
{
    __shared__ float As[16][65];
    __shared__ float Bs[16][65];
    const int tid = threadIdx.x;
    const int tx = tid & 15, ty = tid >> 4;
    const int brow = blockIdx.y * 64, bcol = blockIdx.x * 64;
    const int lr = tid >> 2, lk = (tid & 3) << 2;
    const float* Aptr = A + (size_t)(brow + lr) * K + lk;
    const float* Bptr = Bw + (size_t)(bcol + lr) * K + lk;
    float acc[4][4] = {};
    for (int k0 = 0; k0 < K; k0 += 16) {
        float4 av = *(const float4*)(Aptr + k0);
        float4 bv = *(const float4*)(Bptr + k0);
        As[lk + 0][lr] = av.x; As[lk + 1][lr] = av.y;
        As[lk + 2][lr] = av.z; As[lk + 3][lr] = av.w;
        Bs[lk + 0][lr] = bv.x; Bs[lk + 1][lr] = bv.y;
        Bs[lk + 2][lr] = bv.z; Bs[lk + 3][lr] = bv.w;
        __syncthreads();
#pragma unroll
        for (int kk = 0; kk < 16; ++kk) {
            float a0 = As[kk][ty * 4 + 0], a1 = As[kk][ty * 4 + 1];
            float a2 = As[kk][ty * 4 + 2], a3 = As[kk][ty * 4 + 3];
            float b0 = Bs[kk][tx * 4 + 0], b1 = Bs[kk][tx * 4 + 1];
            float b2 = Bs[kk][tx * 4 + 2], b3 = Bs[kk][tx * 4 + 3];
            acc[0][0] += a0 * b0; acc[0][1] += a0 * b1; acc[0][2] += a0 * b2; acc[0][3] += a0 * b3;
            acc[1][0] += a1 * b0; acc[1][1] += a1 * b1; acc[1][2] += a1 * b2; acc[1][3] += a1 * b3;
            acc[2][0] += a2 * b0; acc[2][1] += a2 * b1; acc[2][2] += a2 * b2; acc[2][3] += a2 * b3;
            acc[3][0] += a3 * b0; acc[3][1] += a3 * b1; acc[3][2] += a3 * b2; acc[3][3] += a3 * b3;
        }
        __syncthreads();
    }
#pragma unroll
    for (int i = 0; i < 4; ++i)
#pragma unroll
        for (int j = 0; j < 4; ++j)
            C[(size_t)(brow + ty * 4 + i) * N + bcol + tx * 4 + j] = acc[i][j];
}

// ---------------------------------------------------------------------------
// Depthwise causal conv (4 taps) over the first DINNER columns of xz, + SiLU.
// xc[r, e] = silu( conv_b[e] + sum_k conv_w[e,k] * xz[r+k-3, e] )  (same b only)
// ---------------------------------------------------------------------------
__global__ __launch_bounds__(256) void conv_silu_kernel(
    const float* __restrict__ xz, const float* __restrict__ conv_w,
    const float* __restrict__ conv_b, float* __restrict__ xc)
{
    const int idx = blockIdx.x * 256 + threadIdx.x;   // r*1024 + e
    const int e = idx & (DINNER - 1);
    const int r = idx >> 10;
    const int l = r & (NL - 1);
    float acc = conv_b[e];
    const float w0 = conv_w[e * 4 + 0], w1 = conv_w[e * 4 + 1];
    const float w2 = conv_w[e * 4 + 2], w3 = conv_w[e * 4 + 3];
    if (l >= 3) acc += w0 * xz[(size_t)(r - 3) * (2 * DINNER) + e];
    if (l >= 2) acc += w1 * xz[(size_t)(r - 2) * (2 * DINNER) + e];
    if (l >= 1) acc += w2 * xz[(size_t)(r - 1) * (2 * DINNER) + e];
    acc += w3 * xz[(size_t)r * (2 * DINNER) + e];
    const float sig = 1.f / (1.f + expf(-acc));
    xc[idx] = acc * sig;
}

// ---------------------------------------------------------------------------
// dbc[r, j] = sum_e xc[r,e] * x_proj_w[j,e]   (j < 64)
// one block (64 threads) per row, row staged in LDS.
// ---------------------------------------------------------------------------
__global__ __launch_bounds__(64) void xproj_kernel(
    const float* __restrict__ xc, const float* __restrict__ W,
    float* __restrict__ dbc)
{
    __shared__ float row[DINNER];
    const int r = blockIdx.x;
    for (int i = threadIdx.x; i < DINNER; i += 64)
        row[i] = xc[(size_t)r * DINNER + i];
    __syncthreads();
    const int j = threadIdx.x;
    const float4* wr4 = (const float4*)(W + (size_t)j * DINNER);
    const float4* row4 = (const float4*)row;
    float4 s = {0.f, 0.f, 0.f, 0.f};
    for (int e4 = 0; e4 < DINNER / 4; ++e4) {
        float4 a = row4[e4];
        float4 w = wr4[e4];
        s.x += a.x * w.x; s.y += a.y * w.y; s.z += a.z * w.z; s.w += a.w * w.w;
    }
    dbc[r * 64 + j] = s.x + s.y + s.z + s.w;
}

// ---------------------------------------------------------------------------
// delta[r, e] = softplus( sum_j dbc[r, j] * dt_proj_w[e, j] + dt_proj_b[e] )
// ---------------------------------------------------------------------------
__global__ __launch_bounds__(256) void delta_kernel(
    const float* __restrict__ dbc, const float* __restrict__ dtw,
    const float* __restrict__ dtb, float* __restrict__ delta)
{
    const int idx = blockIdx.x * 256 + threadIdx.x;   // r*1024 + e
    const int e = idx & (DINNER - 1);
    const int r = idx >> 10;
    const float4* dt4 = (const float4*)(dbc + (size_t)r * 64);
    const float4* w4  = (const float4*)(dtw + (size_t)e * DTRANK);
    float4 s = {0.f, 0.f, 0.f, 0.f};
#pragma unroll
    for (int j4 = 0; j4 < DTRANK / 4; ++j4) {
        float4 a = dt4[j4];
        float4 w = w4[j4];
        s.x += a.x * w.x; s.y += a.y * w.y; s.z += a.z * w.z; s.w += a.w * w.w;
    }
    const float x = s.x + s.y + s.z + s.w + dtb[e];
    // numerically stable softplus
    delta[idx] = fmaxf(x, 0.f) + log1pf(expf(-fabsf(x)));
}

// ---------------------------------------------------------------------------
// Sequential selective scan. 16 lanes per channel (one per state), 16
// channels per 256-thread block. yb aliases delta (read-before-write within
// the same wave iteration).
// ---------------------------------------------------------------------------
__global__ __launch_bounds__(256) void scan_kernel(
    const float* __restrict__ xz, const float* __restrict__ xc,
    const float* __restrict__ dbc, const float* __restrict__ A_log,
    const float* __restrict__ Dp, float* __restrict__ yb /* = delta in, y out */)
{
    const int tid = threadIdx.x;
    const int c = tid >> 4, s = tid & 15;
    const int e = blockIdx.x * 16 + c;
    const int b = blockIdx.y;
    const float Aes = -expf(A_log[e * DSTATE + s]);
    const float Dv = Dp[e];
    float h = 0.f;
    const int rbase = b * NL;
    for (int l = 0; l < NL; ++l) {
        const int r = rbase + l;
        const float dl = yb[(size_t)r * DINNER + e];        // delta
        const float xv = xc[(size_t)r * DINNER + e];
        const float Bv = dbc[r * 64 + DTRANK + s];
        const float Cv = dbc[r * 64 + DTRANK + DSTATE + s];
        const float dA = expf(dl * Aes);
        h = dA * h + (dl * Bv) * xv;
        float p = h * Cv;
        p += __shfl_xor(p, 1, 64);
        p += __shfl_xor(p, 2, 64);
        p += __shfl_xor(p, 4, 64);
        p += __shfl_xor(p, 8, 64);
        if (s == 0) {
            const float y = p + Dv * xv;
            const float zv = xz[(size_t)r * (2 * DINNER) + DINNER + e];
            const float sig = 1.f / (1.f + expf(-zv));
            yb[(size_t)r * DINNER + e] = y * (zv * sig);
        }
    }
}

// ---------------------------------------------------------------------------
extern "C" void kernel_launch(void* const* d_in, const int* in_sizes, int n_in,
                              void* d_out, int out_size, void* d_ws, size_t ws_size,
                              hipStream_t stream)
{
    const float* x          = (const float*)d_in[0];
    const float* in_proj_w  = (const float*)d_in[1];
    const float* conv_w     = (const float*)d_in[2];
    const float* conv_b     = (const float*)d_in[3];
    const float* x_proj_w   = (const float*)d_in[4];
    const float* dt_proj_w  = (const float*)d_in[5];
    const float* dt_proj_b  = (const float*)d_in[6];
    const float* A_log      = (const float*)d_in[7];
    const float* Dp         = (const float*)d_in[8];
    const float* out_proj_w = (const float*)d_in[9];
    float* out = (float*)d_out;

    float* ws  = (float*)d_ws;
    float* xz  = ws;                               // [4096, 2048]
    float* xc  = xz + (size_t)NR * 2 * DINNER;     // [4096, 1024]
    float* dbc = xc + (size_t)NR * DINNER;         // [4096, 64]
    float* yb  = dbc + (size_t)NR * 64;            // [4096, 1024] delta then y

    // 1) xz = x @ in_proj_w^T
    gemm_nt_kernel<<<dim3(2 * DINNER / 64, NR / 64), 256, 0, stream>>>(
        x, in_proj_w, xz, NR, 2 * DINNER, DMODEL);
    // 2) causal depthwise conv + SiLU
    conv_silu_kernel<<<NR * DINNER / 256, 256, 0, stream>>>(xz, conv_w, conv_b, xc);
    // 3) dbc = xc @ x_proj_w^T
    xproj_kernel<<<NR, 64, 0, stream>>>(xc, x_proj_w, dbc);
    // 4) delta = softplus(dt @ dt_proj_w^T + b)
    delta_kernel<<<NR * DINNER / 256, 256, 0, stream>>>(dbc, dt_proj_w, dt_proj_b, yb);
    // 5) selective scan + gate
    scan_kernel<<<dim3(DINNER / 16, NB), 256, 0, stream>>>(xz, xc, dbc, A_log, Dp, yb);
    // 6) out = y @ out_proj_w^T
    gemm_nt_kernel<<<dim3(DMODEL / 64, NR / 64), 256, 0, stream>>>(
        yb, out_proj_w, out, NR, DMODEL, DINNER);
}

// Round 2
// 629.769 us; speedup vs baseline: 2.1552x; 2.1552x over previous
//
#include <hip/hip_runtime.h>
#include <cstddef>

#define DMODEL 512
#define DINNER 1024
#define DSTATE 16
#define DTRANK 32
#define DCONV  4
#define NB     4
#define NL     1024
#define NR     (NB * NL)   // 4096 rows (b*L)
#define CH     128
#define NCHUNK (NL / CH)   // 8

// ---------------------------------------------------------------------------
// C[M,N] = A[M,K] * Bw[N,K]^T   (row-major everywhere, fp32 VALU GEMM)
// ---------------------------------------------------------------------------
__global__ __launch_bounds__(256) void gemm_nt_kernel(
    const float* __restrict__ A, const float* __restrict__ Bw,
    float* __restrict__ C, int M, int N, int K)
{
    __shared__ float As[16][65];
    __shared__ float Bs[16][65];
    const int tid = threadIdx.x;
    const int tx = tid & 15, ty = tid >> 4;
    const int brow = blockIdx.y * 64, bcol = blockIdx.x * 64;
    const int lr = tid >> 2, lk = (tid & 3) << 2;
    const float* Aptr = A + (size_t)(brow + lr) * K + lk;
    const float* Bptr = Bw + (size_t)(bcol + lr) * K + lk;
    float acc[4][4] = {};
    for (int k0 = 0; k0 < K; k0 += 16) {
        float4 av = *(const float4*)(Aptr + k0);
        float4 bv = *(const float4*)(Bptr + k0);
        As[lk + 0][lr] = av.x; As[lk + 1][lr] = av.y;
        As[lk + 2][lr] = av.z; As[lk + 3][lr] = av.w;
        Bs[lk + 0][lr] = bv.x; Bs[lk + 1][lr] = bv.y;
        Bs[lk + 2][lr] = bv.z; Bs[lk + 3][lr] = bv.w;
        __syncthreads();
#pragma unroll
        for (int kk = 0; kk < 16; ++kk) {
            float a0 = As[kk][ty * 4 + 0], a1 = As[kk][ty * 4 + 1];
            float a2 = As[kk][ty * 4 + 2], a3 = As[kk][ty * 4 + 3];
            float b0 = Bs[kk][tx * 4 + 0], b1 = Bs[kk][tx * 4 + 1];
            float b2 = Bs[kk][tx * 4 + 2], b3 = Bs[kk][tx * 4 + 3];
            acc[0][0] += a0 * b0; acc[0][1] += a0 * b1; acc[0][2] += a0 * b2; acc[0][3] += a0 * b3;
            acc[1][0] += a1 * b0; acc[1][1] += a1 * b1; acc[1][2] += a1 * b2; acc[1][3] += a1 * b3;
            acc[2][0] += a2 * b0; acc[2][1] += a2 * b1; acc[2][2] += a2 * b2; acc[2][3] += a2 * b3;
            acc[3][0] += a3 * b0; acc[3][1] += a3 * b1; acc[3][2] += a3 * b2; acc[3][3] += a3 * b3;
        }
        __syncthreads();
    }
#pragma unroll
    for (int i = 0; i < 4; ++i)
#pragma unroll
        for (int j = 0; j < 4; ++j)
            C[(size_t)(brow + ty * 4 + i) * N + bcol + tx * 4 + j] = acc[i][j];
}

// ---------------------------------------------------------------------------
// Depthwise causal conv (4 taps) + SiLU.
// ---------------------------------------------------------------------------
__global__ __launch_bounds__(256) void conv_silu_kernel(
    const float* __restrict__ xz, const float* __restrict__ conv_w,
    const float* __restrict__ conv_b, float* __restrict__ xc)
{
    const int idx = blockIdx.x * 256 + threadIdx.x;   // r*1024 + e
    const int e = idx & (DINNER - 1);
    const int r = idx >> 10;
    const int l = r & (NL - 1);
    float acc = conv_b[e];
    const float w0 = conv_w[e * 4 + 0], w1 = conv_w[e * 4 + 1];
    const float w2 = conv_w[e * 4 + 2], w3 = conv_w[e * 4 + 3];
    if (l >= 3) acc += w0 * xz[(size_t)(r - 3) * (2 * DINNER) + e];
    if (l >= 2) acc += w1 * xz[(size_t)(r - 2) * (2 * DINNER) + e];
    if (l >= 1) acc += w2 * xz[(size_t)(r - 1) * (2 * DINNER) + e];
    acc += w3 * xz[(size_t)r * (2 * DINNER) + e];
    const float sig = 1.f / (1.f + expf(-acc));
    xc[idx] = acc * sig;
}

// ---------------------------------------------------------------------------
// dbc[r, j] = sum_e xc[r,e] * x_proj_w[j,e]   (j < 64)
// ---------------------------------------------------------------------------
__global__ __launch_bounds__(64) void xproj_kernel(
    const float* __restrict__ xc, const float* __restrict__ W,
    float* __restrict__ dbc)
{
    __shared__ float row[DINNER];
    const int r = blockIdx.x;
    for (int i = threadIdx.x; i < DINNER; i += 64)
        row[i] = xc[(size_t)r * DINNER + i];
    __syncthreads();
    const int j = threadIdx.x;
    const float4* wr4 = (const float4*)(W + (size_t)j * DINNER);
    const float4* row4 = (const float4*)row;
    float4 s = {0.f, 0.f, 0.f, 0.f};
    for (int e4 = 0; e4 < DINNER / 4; ++e4) {
        float4 a = row4[e4];
        float4 w = wr4[e4];
        s.x += a.x * w.x; s.y += a.y * w.y; s.z += a.z * w.z; s.w += a.w * w.w;
    }
    dbc[r * 64 + j] = s.x + s.y + s.z + s.w;
}

// ---------------------------------------------------------------------------
// delta[r, e] = softplus( sum_j dbc[r, j] * dt_proj_w[e, j] + dt_proj_b[e] )
// ---------------------------------------------------------------------------
__global__ __launch_bounds__(256) void delta_kernel(
    const float* __restrict__ dbc, const float* __restrict__ dtw,
    const float* __restrict__ dtb, float* __restrict__ delta)
{
    const int idx = blockIdx.x * 256 + threadIdx.x;   // r*1024 + e
    const int e = idx & (DINNER - 1);
    const int r = idx >> 10;
    const float4* dt4 = (const float4*)(dbc + (size_t)r * 64);
    const float4* w4  = (const float4*)(dtw + (size_t)e * DTRANK);
    float4 s = {0.f, 0.f, 0.f, 0.f};
#pragma unroll
    for (int j4 = 0; j4 < DTRANK / 4; ++j4) {
        float4 a = dt4[j4];
        float4 w = w4[j4];
        s.x += a.x * w.x; s.y += a.y * w.y; s.z += a.z * w.z; s.w += a.w * w.w;
    }
    const float x = s.x + s.y + s.z + s.w + dtb[e];
    delta[idx] = fmaxf(x, 0.f) + log1pf(expf(-fabsf(x)));
}

// ---------------------------------------------------------------------------
// Chunked scan, phase A: per chunk, P = prod(dA), S = local scan end (h0=0).
// grid (DINNER/16, NB, NCHUNK), 256 thr = 16 channels x 16 states.
// ---------------------------------------------------------------------------
__global__ __launch_bounds__(256) void scanA_kernel(
    const float* __restrict__ delta, const float* __restrict__ xc,
    const float* __restrict__ dbc, const float* __restrict__ A_log,
    float* __restrict__ chunkP, float* __restrict__ chunkS)
{
    const int tid = threadIdx.x;
    const int c = tid >> 4, s = tid & 15;
    const int e = blockIdx.x * 16 + c;
    const int b = blockIdx.y, ck = blockIdx.z;
    const float Aes = -expf(A_log[e * DSTATE + s]);
    const int rbase = b * NL + ck * CH;
    const float* dp = delta + (size_t)rbase * DINNER + e;
    const float* xp = xc + (size_t)rbase * DINNER + e;
    const float* bp = dbc + (size_t)rbase * 64 + DTRANK + s;
    float P = 1.f, S = 0.f;
#pragma unroll 4
    for (int l = 0; l < CH; ++l) {
        const float dl = dp[(size_t)l * DINNER];
        const float xv = xp[(size_t)l * DINNER];
        const float Bv = bp[(size_t)l * 64];
        const float dA = expf(dl * Aes);
        P *= dA;
        S = fmaf(dA, S, dl * Bv * xv);
    }
    const size_t oi = (((size_t)b * NCHUNK + ck) * DINNER + e) * DSTATE + s;
    chunkP[oi] = P;
    chunkS[oi] = S;
}

// ---------------------------------------------------------------------------
// Phase B: serial scan over NCHUNK chunk summaries per (b,e,s).
// chunkS is rewritten in place to hold h_init (h at chunk START).
// ---------------------------------------------------------------------------
__global__ __launch_bounds__(256) void scanB_kernel(
    const float* __restrict__ chunkP, float* __restrict__ chunkS)
{
    const int idx = blockIdx.x * 256 + threadIdx.x;    // b*(DINNER*16) + e*16 + s
    const int b = idx >> 14;                            // / (DINNER*DSTATE)
    const int rem = idx & (DINNER * DSTATE - 1);
    float h = 0.f;
#pragma unroll
    for (int c = 0; c < NCHUNK; ++c) {
        const size_t i = ((size_t)(b * NCHUNK + c) * DINNER * DSTATE) + rem;
        const float P = chunkP[i];
        const float S = chunkS[i];
        chunkS[i] = h;                // h at chunk start
        h = fmaf(P, h, S);
    }
}

// ---------------------------------------------------------------------------
// Phase C: re-scan each chunk from h_init, compute gated y (overwrites delta).
// ---------------------------------------------------------------------------
__global__ __launch_bounds__(256) void scanC_kernel(
    const float* __restrict__ xz, const float* __restrict__ xc,
    const float* __restrict__ dbc, const float* __restrict__ A_log,
    const float* __restrict__ Dp, const float* __restrict__ hinit,
    float* __restrict__ yb /* delta in, y out */)
{
    const int tid = threadIdx.x;
    const int c = tid >> 4, s = tid & 15;
    const int e = blockIdx.x * 16 + c;
    const int b = blockIdx.y, ck = blockIdx.z;
    const float Aes = -expf(A_log[e * DSTATE + s]);
    const float Dv = Dp[e];
    const int rbase = b * NL + ck * CH;
    const size_t oi = (((size_t)b * NCHUNK + ck) * DINNER + e) * DSTATE + s;
    float h = hinit[oi];
    const float* bp = dbc + (size_t)rbase * 64 + DTRANK + s;
    const float* cp = dbc + (size_t)rbase * 64 + DTRANK + DSTATE + s;
#pragma unroll 2
    for (int l = 0; l < CH; ++l) {
        const size_t r = rbase + l;
        const float dl = yb[r * DINNER + e];
        const float xv = xc[r * DINNER + e];
        const float Bv = bp[(size_t)l * 64];
        const float Cv = cp[(size_t)l * 64];
        const float dA = expf(dl * Aes);
        h = fmaf(dA, h, dl * Bv * xv);
        float p = h * Cv;
        p += __shfl_xor(p, 1, 64);
        p += __shfl_xor(p, 2, 64);
        p += __shfl_xor(p, 4, 64);
        p += __shfl_xor(p, 8, 64);
        if (s == 0) {
            const float y = p + Dv * xv;
            const float zv = xz[r * (2 * DINNER) + DINNER + e];
            const float sig = 1.f / (1.f + expf(-zv));
            yb[r * DINNER + e] = y * (zv * sig);
        }
    }
}

// ---------------------------------------------------------------------------
extern "C" void kernel_launch(void* const* d_in, const int* in_sizes, int n_in,
                              void* d_out, int out_size, void* d_ws, size_t ws_size,
                              hipStream_t stream)
{
    const float* x          = (const float*)d_in[0];
    const float* in_proj_w  = (const float*)d_in[1];
    const float* conv_w     = (const float*)d_in[2];
    const float* conv_b     = (const float*)d_in[3];
    const float* x_proj_w   = (const float*)d_in[4];
    const float* dt_proj_w  = (const float*)d_in[5];
    const float* dt_proj_b  = (const float*)d_in[6];
    const float* A_log      = (const float*)d_in[7];
    const float* Dp         = (const float*)d_in[8];
    const float* out_proj_w = (const float*)d_in[9];
    float* out = (float*)d_out;

    float* ws  = (float*)d_ws;
    float* xz  = ws;                               // [4096, 2048]
    float* xc  = xz + (size_t)NR * 2 * DINNER;     // [4096, 1024]
    float* dbc = xc + (size_t)NR * DINNER;         // [4096, 64]
    float* yb  = dbc + (size_t)NR * 64;            // [4096, 1024] delta then y
    float* wsend = yb + (size_t)NR * DINNER;

    const size_t chunk_elems = (size_t)NB * NCHUNK * DINNER * DSTATE;  // 512K floats
    const size_t used = (size_t)(wsend - ws) + 2 * chunk_elems;
    float* chunkP;
    float* chunkS;
    if (ws_size >= used * sizeof(float)) {
        chunkP = wsend;
        chunkS = wsend + chunk_elems;
    } else {
        // d_out (8 MB) as scratch; fully overwritten by the final GEMM.
        chunkP = out;
        chunkS = out + chunk_elems;
    }

    // 1) xz = x @ in_proj_w^T
    gemm_nt_kernel<<<dim3(2 * DINNER / 64, NR / 64), 256, 0, stream>>>(
        x, in_proj_w, xz, NR, 2 * DINNER, DMODEL);
    // 2) causal depthwise conv + SiLU
    conv_silu_kernel<<<NR * DINNER / 256, 256, 0, stream>>>(xz, conv_w, conv_b, xc);
    // 3) dbc = xc @ x_proj_w^T
    xproj_kernel<<<NR, 64, 0, stream>>>(xc, x_proj_w, dbc);
    // 4) delta = softplus(dt @ dt_proj_w^T + b)
    delta_kernel<<<NR * DINNER / 256, 256, 0, stream>>>(dbc, dt_proj_w, dt_proj_b, yb);
    // 5) chunked parallel scan
    scanA_kernel<<<dim3(DINNER / 16, NB, NCHUNK), 256, 0, stream>>>(
        yb, xc, dbc, A_log, chunkP, chunkS);
    scanB_kernel<<<NB * DINNER * DSTATE / 256, 256, 0, stream>>>(chunkP, chunkS);
    scanC_kernel<<<dim3(DINNER / 16, NB, NCHUNK), 256, 0, stream>>>(
        xz, xc, dbc, A_log, Dp, chunkS, yb);
    // 6) out = y @ out_proj_w^T
    gemm_nt_kernel<<<dim3(DMODEL / 64, NR / 64), 256, 0, stream>>>(
        yb, out_proj_w, out, NR, DMODEL, DINNER);
}

// Round 3
// 416.982 us; speedup vs baseline: 3.2550x; 1.5103x over previous
//
#include <hip/hip_runtime.h>
#include <cstddef>
#include <cstdint>

#define DMODEL 512
#define DINNER 1024
#define DSTATE 16
#define DTRANK 32
#define DCONV  4
#define NB     4
#define NL     1024
#define NR     (NB * NL)   // 4096 rows (b*L)
#define CH     128
#define NCHUNK (NL / CH)   // 8

typedef __attribute__((ext_vector_type(8))) short bf16x8;   // 8 bf16 in 4 VGPRs
typedef __attribute__((ext_vector_type(4))) float f32x4;

__device__ __forceinline__ unsigned short f2bf(float f) {
    unsigned u = __builtin_bit_cast(unsigned, f);
    unsigned r = u + 0x7FFFu + ((u >> 16) & 1u);   // RNE
    return (unsigned short)(r >> 16);
}

__device__ __forceinline__ void gload_lds16(const unsigned short* g, unsigned short* lds) {
    __builtin_amdgcn_global_load_lds(
        (const __attribute__((address_space(1))) void*)g,
        (__attribute__((address_space(3))) void*)lds, 16, 0, 0);
}

// ---------------------------------------------------------------------------
// fp32 -> bf16 cast (vectorized), n4 = n/4
// ---------------------------------------------------------------------------
__global__ __launch_bounds__(256) void cast_bf16_kernel(
    const float* __restrict__ in, unsigned short* __restrict__ out, int n4)
{
    const int i = blockIdx.x * 256 + threadIdx.x;
    if (i >= n4) return;
    float4 v = ((const float4*)in)[i];
    ushort4 o;
    o.x = f2bf(v.x); o.y = f2bf(v.y); o.z = f2bf(v.z); o.w = f2bf(v.w);
    ((ushort4*)out)[i] = o;
}

// ---------------------------------------------------------------------------
// bf16 MFMA GEMM: C[M,N] = A[M,K] * Bw[N,K]^T, fp32 out.
// BM=128, BK=64, 256 threads (4 waves, 2x2), per-wave 64 x BN/2 output.
// global_load_lds(16B) staging, XOR-8 swizzle via pre-swizzled global source
// (LDS dest stays linear), swizzled ds_read_b128 fragment loads.
// Requires M%128==0, N%BN==0, K%64==0.
// ---------------------------------------------------------------------------
template<int BN>
__global__ __launch_bounds__(256) void gemm_bf16_kernel(
    const unsigned short* __restrict__ A, const unsigned short* __restrict__ Bw,
    float* __restrict__ C, int M, int N, int K)
{
    constexpr int BK = 64;                  // k per staged tile (8 slots of 8)
    constexpr int NFRAG = BN / 32;          // per-wave 16-col fragments
    constexpr int BINSTR = BN / 32;         // global_load_lds per wave for B
    __shared__ unsigned short As[128 * BK];
    __shared__ unsigned short Bs[BN * BK];

    const int tid  = threadIdx.x;
    const int lane = tid & 63;
    const int w    = tid >> 6;
    const int wm   = w >> 1, wn = w & 1;
    const int brow = blockIdx.y * 128;
    const int bcol = blockIdx.x * BN;

    // staging: chunk c -> LDS row r=c>>3, slot c&7; source slot = (c&7)^(r&7).
    // r&7 == lane>>3 for all our instr groups, so:
    const int srcslot = (lane & 7) ^ (lane >> 3);
    const unsigned short* ag[4];
    unsigned short* al[4];
#pragma unroll
    for (int i = 0; i < 4; ++i) {
        const int r = w * 32 + i * 8 + (lane >> 3);
        ag[i] = A + (size_t)(brow + r) * K + srcslot * 8;
        al[i] = As + (w * 256 + i * 64) * 8;      // wave-uniform base
    }
    const unsigned short* bg[BINSTR];
    unsigned short* bl[BINSTR];
#pragma unroll
    for (int i = 0; i < BINSTR; ++i) {
        const int r = w * 8 * BINSTR + i * 8 + (lane >> 3);
        bg[i] = Bw + (size_t)(bcol + r) * K + srcslot * 8;
        bl[i] = Bs + (w * 64 * BINSTR + i * 64) * 8;
    }

    // fragment read offsets
    const int fr = lane & 15;        // row within 16
    const int fq = lane >> 4;        // k sub-slot 0..3
    f32x4 acc[4][NFRAG] = {};

    for (int k0 = 0; k0 < K; k0 += BK) {
#pragma unroll
        for (int i = 0; i < 4; ++i) gload_lds16(ag[i] + k0, al[i]);
#pragma unroll
        for (int i = 0; i < BINSTR; ++i) gload_lds16(bg[i] + k0, bl[i]);
        __syncthreads();   // drains vmcnt before any wave reads LDS
#pragma unroll
        for (int ks = 0; ks < 2; ++ks) {
            bf16x8 af[4], bfr[NFRAG];
#pragma unroll
            for (int m = 0; m < 4; ++m) {
                const int r = wm * 64 + m * 16 + fr;
                const int s = (ks * 4 + fq) ^ (r & 7);
                af[m] = *(const bf16x8*)(As + r * BK + s * 8);
            }
#pragma unroll
            for (int n = 0; n < NFRAG; ++n) {
                const int r = wn * (BN / 2) + n * 16 + fr;
                const int s = (ks * 4 + fq) ^ (r & 7);
                bfr[n] = *(const bf16x8*)(Bs + r * BK + s * 8);
            }
#pragma unroll
            for (int m = 0; m < 4; ++m)
#pragma unroll
                for (int n = 0; n < NFRAG; ++n)
                    acc[m][n] = __builtin_amdgcn_mfma_f32_16x16x32_bf16(
                        af[m], bfr[n], acc[m][n], 0, 0, 0);
        }
        __syncthreads();
    }

    // C/D layout: col = lane&15, row = (lane>>4)*4 + j
    const int row0 = brow + wm * 64;
    const int col0 = bcol + wn * (BN / 2);
#pragma unroll
    for (int m = 0; m < 4; ++m)
#pragma unroll
        for (int n = 0; n < NFRAG; ++n)
#pragma unroll
            for (int j = 0; j < 4; ++j)
                C[(size_t)(row0 + m * 16 + fq * 4 + j) * N + col0 + n * 16 + fr] = acc[m][n][j];
}

// ---------------------------------------------------------------------------
// Depthwise causal conv (4 taps) + SiLU.
// ---------------------------------------------------------------------------
__global__ __launch_bounds__(256) void conv_silu_kernel(
    const float* __restrict__ xz, const float* __restrict__ conv_w,
    const float* __restrict__ conv_b, float* __restrict__ xc)
{
    const int idx = blockIdx.x * 256 + threadIdx.x;   // r*1024 + e
    const int e = idx & (DINNER - 1);
    const int r = idx >> 10;
    const int l = r & (NL - 1);
    float acc = conv_b[e];
    const float w0 = conv_w[e * 4 + 0], w1 = conv_w[e * 4 + 1];
    const float w2 = conv_w[e * 4 + 2], w3 = conv_w[e * 4 + 3];
    if (l >= 3) acc += w0 * xz[(size_t)(r - 3) * (2 * DINNER) + e];
    if (l >= 2) acc += w1 * xz[(size_t)(r - 2) * (2 * DINNER) + e];
    if (l >= 1) acc += w2 * xz[(size_t)(r - 1) * (2 * DINNER) + e];
    acc += w3 * xz[(size_t)r * (2 * DINNER) + e];
    const float sig = 1.f / (1.f + expf(-acc));
    xc[idx] = acc * sig;
}

// ---------------------------------------------------------------------------
// dbc[r, j] = sum_e xc[r,e] * x_proj_w[j,e]   (j < 64)
// ---------------------------------------------------------------------------
__global__ __launch_bounds__(64) void xproj_kernel(
    const float* __restrict__ xc, const float* __restrict__ W,
    float* __restrict__ dbc)
{
    __shared__ float row[DINNER];
    const int r = blockIdx.x;
    for (int i = threadIdx.x; i < DINNER; i += 64)
        row[i] = xc[(size_t)r * DINNER + i];
    __syncthreads();
    const int j = threadIdx.x;
    const float4* wr4 = (const float4*)(W + (size_t)j * DINNER);
    const float4* row4 = (const float4*)row;
    float4 s = {0.f, 0.f, 0.f, 0.f};
    for (int e4 = 0; e4 < DINNER / 4; ++e4) {
        float4 a = row4[e4];
        float4 w = wr4[e4];
        s.x += a.x * w.x; s.y += a.y * w.y; s.z += a.z * w.z; s.w += a.w * w.w;
    }
    dbc[r * 64 + j] = s.x + s.y + s.z + s.w;
}

// ---------------------------------------------------------------------------
// delta[r, e] = softplus( sum_j dbc[r, j] * dt_proj_w[e, j] + dt_proj_b[e] )
// ---------------------------------------------------------------------------
__global__ __launch_bounds__(256) void delta_kernel(
    const float* __restrict__ dbc, const float* __restrict__ dtw,
    const float* __restrict__ dtb, float* __restrict__ delta)
{
    const int idx = blockIdx.x * 256 + threadIdx.x;   // r*1024 + e
    const int e = idx & (DINNER - 1);
    const int r = idx >> 10;
    const float4* dt4 = (const float4*)(dbc + (size_t)r * 64);
    const float4* w4  = (const float4*)(dtw + (size_t)e * DTRANK);
    float4 s = {0.f, 0.f, 0.f, 0.f};
#pragma unroll
    for (int j4 = 0; j4 < DTRANK / 4; ++j4) {
        float4 a = dt4[j4];
        float4 w = w4[j4];
        s.x += a.x * w.x; s.y += a.y * w.y; s.z += a.z * w.z; s.w += a.w * w.w;
    }
    const float x = s.x + s.y + s.z + s.w + dtb[e];
    delta[idx] = fmaxf(x, 0.f) + log1pf(expf(-fabsf(x)));
}

// ---------------------------------------------------------------------------
// Chunked scan, phase A: per chunk, P = prod(dA), S = local scan end (h0=0).
// ---------------------------------------------------------------------------
__global__ __launch_bounds__(256) void scanA_kernel(
    const float* __restrict__ delta, const float* __restrict__ xc,
    const float* __restrict__ dbc, const float* __restrict__ A_log,
    float* __restrict__ chunkP, float* __restrict__ chunkS)
{
    const int tid = threadIdx.x;
    const int c = tid >> 4, s = tid & 15;
    const int e = blockIdx.x * 16 + c;
    const int b = blockIdx.y, ck = blockIdx.z;
    const float Aes = -expf(A_log[e * DSTATE + s]);
    const int rbase = b * NL + ck * CH;
    const float* dp = delta + (size_t)rbase * DINNER + e;
    const float* xp = xc + (size_t)rbase * DINNER + e;
    const float* bp = dbc + (size_t)rbase * 64 + DTRANK + s;
    float P = 1.f, S = 0.f;
#pragma unroll 4
    for (int l = 0; l < CH; ++l) {
        const float dl = dp[(size_t)l * DINNER];
        const float xv = xp[(size_t)l * DINNER];
        const float Bv = bp[(size_t)l * 64];
        const float dA = expf(dl * Aes);
        P *= dA;
        S = fmaf(dA, S, dl * Bv * xv);
    }
    const size_t oi = (((size_t)b * NCHUNK + ck) * DINNER + e) * DSTATE + s;
    chunkP[oi] = P;
    chunkS[oi] = S;
}

// ---------------------------------------------------------------------------
// Phase B: serial scan over NCHUNK chunk summaries per (b,e,s).
// ---------------------------------------------------------------------------
__global__ __launch_bounds__(256) void scanB_kernel(
    const float* __restrict__ chunkP, float* __restrict__ chunkS)
{
    const int idx = blockIdx.x * 256 + threadIdx.x;
    const int b = idx >> 14;
    const int rem = idx & (DINNER * DSTATE - 1);
    float h = 0.f;
#pragma unroll
    for (int c = 0; c < NCHUNK; ++c) {
        const size_t i = ((size_t)(b * NCHUNK + c) * DINNER * DSTATE) + rem;
        const float P = chunkP[i];
        const float S = chunkS[i];
        chunkS[i] = h;                // h at chunk start
        h = fmaf(P, h, S);
    }
}

// ---------------------------------------------------------------------------
// Phase C: re-scan each chunk from h_init, gated y written as bf16.
// ---------------------------------------------------------------------------
__global__ __launch_bounds__(256) void scanC_kernel(
    const float* __restrict__ xz, const float* __restrict__ xc,
    const float* __restrict__ dbc, const float* __restrict__ A_log,
    const float* __restrict__ Dp, const float* __restrict__ hinit,
    const float* __restrict__ delta, unsigned short* __restrict__ yh)
{
    const int tid = threadIdx.x;
    const int c = tid >> 4, s = tid & 15;
    const int e = blockIdx.x * 16 + c;
    const int b = blockIdx.y, ck = blockIdx.z;
    const float Aes = -expf(A_log[e * DSTATE + s]);
    const float Dv = Dp[e];
    const int rbase = b * NL + ck * CH;
    const size_t oi = (((size_t)b * NCHUNK + ck) * DINNER + e) * DSTATE + s;
    float h = hinit[oi];
    const float* bp = dbc + (size_t)rbase * 64 + DTRANK + s;
    const float* cp = dbc + (size_t)rbase * 64 + DTRANK + DSTATE + s;
#pragma unroll 2
    for (int l = 0; l < CH; ++l) {
        const size_t r = rbase + l;
        const float dl = delta[r * DINNER + e];
        const float xv = xc[r * DINNER + e];
        const float Bv = bp[(size_t)l * 64];
        const float Cv = cp[(size_t)l * 64];
        const float dA = expf(dl * Aes);
        h = fmaf(dA, h, dl * Bv * xv);
        float p = h * Cv;
        p += __shfl_xor(p, 1, 64);
        p += __shfl_xor(p, 2, 64);
        p += __shfl_xor(p, 4, 64);
        p += __shfl_xor(p, 8, 64);
        if (s == 0) {
            const float y = p + Dv * xv;
            const float zv = xz[r * (2 * DINNER) + DINNER + e];
            const float sig = 1.f / (1.f + expf(-zv));
            yh[r * DINNER + e] = f2bf(y * (zv * sig));
        }
    }
}

// ---------------------------------------------------------------------------
extern "C" void kernel_launch(void* const* d_in, const int* in_sizes, int n_in,
                              void* d_out, int out_size, void* d_ws, size_t ws_size,
                              hipStream_t stream)
{
    const float* x          = (const float*)d_in[0];
    const float* in_proj_w  = (const float*)d_in[1];
    const float* conv_w     = (const float*)d_in[2];
    const float* conv_b     = (const float*)d_in[3];
    const float* x_proj_w   = (const float*)d_in[4];
    const float* dt_proj_w  = (const float*)d_in[5];
    const float* dt_proj_b  = (const float*)d_in[6];
    const float* A_log      = (const float*)d_in[7];
    const float* Dp         = (const float*)d_in[8];
    const float* out_proj_w = (const float*)d_in[9];
    float* out = (float*)d_out;

    float* ws  = (float*)d_ws;
    float* xz  = ws;                               // [4096, 2048] fp32
    float* xc  = xz + (size_t)NR * 2 * DINNER;     // [4096, 1024] fp32
    float* dbc = xc + (size_t)NR * DINNER;         // [4096, 64]
    float* yb  = dbc + (size_t)NR * 64;            // [4096, 1024] delta fp32
    float* chunkP = yb + (size_t)NR * DINNER;      // [4, 8, 1024, 16]
    float* chunkS = chunkP + (size_t)NB * NCHUNK * DINNER * DSTATE;
    unsigned short* xh  = (unsigned short*)(chunkS + (size_t)NB * NCHUNK * DINNER * DSTATE);
    unsigned short* wih = xh + (size_t)NR * DMODEL;          // [2048, 512] bf16
    unsigned short* woh = wih + (size_t)2 * DINNER * DMODEL; // [512, 1024] bf16
    unsigned short* yh  = woh + (size_t)DMODEL * DINNER;     // [4096, 1024] bf16
    // total ws use ~84 MB

    // 0) casts to bf16
    cast_bf16_kernel<<<(NR * DMODEL / 4 + 255) / 256, 256, 0, stream>>>(x, xh, NR * DMODEL / 4);
    cast_bf16_kernel<<<(2 * DINNER * DMODEL / 4 + 255) / 256, 256, 0, stream>>>(
        in_proj_w, wih, 2 * DINNER * DMODEL / 4);
    cast_bf16_kernel<<<(DMODEL * DINNER / 4 + 255) / 256, 256, 0, stream>>>(
        out_proj_w, woh, DMODEL * DINNER / 4);

    // 1) xz = x @ in_proj_w^T  (bf16 MFMA)
    gemm_bf16_kernel<128><<<dim3(2 * DINNER / 128, NR / 128), 256, 0, stream>>>(
        xh, wih, xz, NR, 2 * DINNER, DMODEL);
    // 2) causal depthwise conv + SiLU
    conv_silu_kernel<<<NR * DINNER / 256, 256, 0, stream>>>(xz, conv_w, conv_b, xc);
    // 3) dbc = xc @ x_proj_w^T
    xproj_kernel<<<NR, 64, 0, stream>>>(xc, x_proj_w, dbc);
    // 4) delta = softplus(dt @ dt_proj_w^T + b)
    delta_kernel<<<NR * DINNER / 256, 256, 0, stream>>>(dbc, dt_proj_w, dt_proj_b, yb);
    // 5) chunked parallel scan (writes y as bf16)
    scanA_kernel<<<dim3(DINNER / 16, NB, NCHUNK), 256, 0, stream>>>(
        yb, xc, dbc, A_log, chunkP, chunkS);
    scanB_kernel<<<NB * DINNER * DSTATE / 256, 256, 0, stream>>>(chunkP, chunkS);
    scanC_kernel<<<dim3(DINNER / 16, NB, NCHUNK), 256, 0, stream>>>(
        xz, xc, dbc, A_log, Dp, chunkS, yb, yh);
    // 6) out = y @ out_proj_w^T  (bf16 MFMA)
    gemm_bf16_kernel<64><<<dim3(DMODEL / 64, NR / 128), 256, 0, stream>>>(
        yh, woh, out, NR, DMODEL, DINNER);
}

// Round 4
// 152.838 us; speedup vs baseline: 8.8805x; 2.7283x over previous
//
#include <hip/hip_runtime.h>
#include <cstddef>
#include <cstdint>

#define DMODEL 512
#define DINNER 1024
#define DSTATE 16
#define DTRANK 32
#define DCONV  4
#define NB     4
#define NL     1024
#define NR     (NB * NL)   // 4096 rows (b*L)
#define CH     32
#define NCHUNK (NL / CH)   // 32
#define LOG2E  1.4426950408889634f

typedef __attribute__((ext_vector_type(8))) short bf16x8;   // 8 bf16 in 4 VGPRs
typedef __attribute__((ext_vector_type(4))) float f32x4;

__device__ __forceinline__ unsigned short f2bf(float f) {
    unsigned u = __builtin_bit_cast(unsigned, f);
    unsigned r = u + 0x7FFFu + ((u >> 16) & 1u);   // RNE
    return (unsigned short)(r >> 16);
}

__device__ __forceinline__ void gload_lds16(const unsigned short* g, unsigned short* lds) {
    __builtin_amdgcn_global_load_lds(
        (const __attribute__((address_space(1))) void*)g,
        (__attribute__((address_space(3))) void*)lds, 16, 0, 0);
}

// ---------------------------------------------------------------------------
// fp32 -> bf16 cast (vectorized), n4 = n/4
// ---------------------------------------------------------------------------
__global__ __launch_bounds__(256) void cast_bf16_kernel(
    const float* __restrict__ in, unsigned short* __restrict__ out, int n4)
{
    const int i = blockIdx.x * 256 + threadIdx.x;
    if (i >= n4) return;
    float4 v = ((const float4*)in)[i];
    ushort4 o;
    o.x = f2bf(v.x); o.y = f2bf(v.y); o.z = f2bf(v.z); o.w = f2bf(v.w);
    ((ushort4*)out)[i] = o;
}

// ---------------------------------------------------------------------------
// bf16 MFMA GEMM: C[M,N] = A[M,K] * Bw[N,K]^T, fp32 out. (unchanged from r3)
// ---------------------------------------------------------------------------
template<int BN>
__global__ __launch_bounds__(256) void gemm_bf16_kernel(
    const unsigned short* __restrict__ A, const unsigned short* __restrict__ Bw,
    float* __restrict__ C, int M, int N, int K)
{
    constexpr int BK = 64;
    constexpr int NFRAG = BN / 32;
    constexpr int BINSTR = BN / 32;
    __shared__ unsigned short As[128 * BK];
    __shared__ unsigned short Bs[BN * BK];

    const int tid  = threadIdx.x;
    const int lane = tid & 63;
    const int w    = tid >> 6;
    const int wm   = w >> 1, wn = w & 1;
    const int brow = blockIdx.y * 128;
    const int bcol = blockIdx.x * BN;

    const int srcslot = (lane & 7) ^ (lane >> 3);
    const unsigned short* ag[4];
    unsigned short* al[4];
#pragma unroll
    for (int i = 0; i < 4; ++i) {
        const int r = w * 32 + i * 8 + (lane >> 3);
        ag[i] = A + (size_t)(brow + r) * K + srcslot * 8;
        al[i] = As + (w * 256 + i * 64) * 8;
    }
    const unsigned short* bg[BINSTR];
    unsigned short* bl[BINSTR];
#pragma unroll
    for (int i = 0; i < BINSTR; ++i) {
        const int r = w * 8 * BINSTR + i * 8 + (lane >> 3);
        bg[i] = Bw + (size_t)(bcol + r) * K + srcslot * 8;
        bl[i] = Bs + (w * 64 * BINSTR + i * 64) * 8;
    }

    const int fr = lane & 15;
    const int fq = lane >> 4;
    f32x4 acc[4][NFRAG] = {};

    for (int k0 = 0; k0 < K; k0 += BK) {
#pragma unroll
        for (int i = 0; i < 4; ++i) gload_lds16(ag[i] + k0, al[i]);
#pragma unroll
        for (int i = 0; i < BINSTR; ++i) gload_lds16(bg[i] + k0, bl[i]);
        __syncthreads();
#pragma unroll
        for (int ks = 0; ks < 2; ++ks) {
            bf16x8 af[4], bfr[NFRAG];
#pragma unroll
            for (int m = 0; m < 4; ++m) {
                const int r = wm * 64 + m * 16 + fr;
                const int s = (ks * 4 + fq) ^ (r & 7);
                af[m] = *(const bf16x8*)(As + r * BK + s * 8);
            }
#pragma unroll
            for (int n = 0; n < NFRAG; ++n) {
                const int r = wn * (BN / 2) + n * 16 + fr;
                const int s = (ks * 4 + fq) ^ (r & 7);
                bfr[n] = *(const bf16x8*)(Bs + r * BK + s * 8);
            }
#pragma unroll
            for (int m = 0; m < 4; ++m)
#pragma unroll
                for (int n = 0; n < NFRAG; ++n)
                    acc[m][n] = __builtin_amdgcn_mfma_f32_16x16x32_bf16(
                        af[m], bfr[n], acc[m][n], 0, 0, 0);
        }
        __syncthreads();
    }

    const int row0 = brow + wm * 64;
    const int col0 = bcol + wn * (BN / 2);
#pragma unroll
    for (int m = 0; m < 4; ++m)
#pragma unroll
        for (int n = 0; n < NFRAG; ++n)
#pragma unroll
            for (int j = 0; j < 4; ++j)
                C[(size_t)(row0 + m * 16 + fq * 4 + j) * N + col0 + n * 16 + fr] = acc[m][n][j];
}

// ---------------------------------------------------------------------------
// Depthwise causal conv (4 taps) + SiLU (fast exp2/rcp sigmoid).
// ---------------------------------------------------------------------------
__global__ __launch_bounds__(256) void conv_silu_kernel(
    const float* __restrict__ xz, const float* __restrict__ conv_w,
    const float* __restrict__ conv_b, float* __restrict__ xc)
{
    const int idx = blockIdx.x * 256 + threadIdx.x;   // r*1024 + e
    const int e = idx & (DINNER - 1);
    const int r = idx >> 10;
    const int l = r & (NL - 1);
    float acc = conv_b[e];
    const float w0 = conv_w[e * 4 + 0], w1 = conv_w[e * 4 + 1];
    const float w2 = conv_w[e * 4 + 2], w3 = conv_w[e * 4 + 3];
    if (l >= 3) acc += w0 * xz[(size_t)(r - 3) * (2 * DINNER) + e];
    if (l >= 2) acc += w1 * xz[(size_t)(r - 2) * (2 * DINNER) + e];
    if (l >= 1) acc += w2 * xz[(size_t)(r - 1) * (2 * DINNER) + e];
    acc += w3 * xz[(size_t)r * (2 * DINNER) + e];
    const float sig = __builtin_amdgcn_rcpf(1.f + __builtin_amdgcn_exp2f(-acc * LOG2E));
    xc[idx] = acc * sig;
}

// ---------------------------------------------------------------------------
// Fused xproj + delta: per block, XPR=8 rows.
//   dbc[r,0:64]  = xc[r,:] . x_proj_w[j,:]
//   delta[r,e]   = softplus(dbc[r,0:32] . dt_proj_w[e,:] + dt_proj_b[e])
// ---------------------------------------------------------------------------
#define XPR 8
__global__ __launch_bounds__(256) void xpd_kernel(
    const float* __restrict__ xc, const float* __restrict__ W,
    const float* __restrict__ dtw, const float* __restrict__ dtb,
    float* __restrict__ dbc, float* __restrict__ delta)
{
    __shared__ float xr[XPR * DINNER];     // 32 KB
    __shared__ float psum[XPR * 256];      // [row][part*64+j]
    __shared__ float dlds[XPR * DTRANK];
    const int t = threadIdx.x;
    const int r0 = blockIdx.x * XPR;

    const float4* xc4 = (const float4*)(xc + (size_t)r0 * DINNER);
    float4* xr4 = (float4*)xr;
    for (int i = t; i < XPR * DINNER / 4; i += 256) xr4[i] = xc4[i];
    __syncthreads();

    const int j = t & 63, part = t >> 6;
    float acc[XPR];
#pragma unroll
    for (int row = 0; row < XPR; ++row) acc[row] = 0.f;
    const float4* w4  = (const float4*)(W + (size_t)j * DINNER) + part * 64;
    const float4* xb4 = (const float4*)xr + part * 64;
    for (int i = 0; i < 64; ++i) {
        const float4 w = w4[i];
#pragma unroll
        for (int row = 0; row < XPR; ++row) {
            const float4 xv = xb4[row * 256 + i];
            acc[row] += w.x * xv.x + w.y * xv.y + w.z * xv.z + w.w * xv.w;
        }
    }
#pragma unroll
    for (int row = 0; row < XPR; ++row) psum[row * 256 + part * 64 + j] = acc[row];
    __syncthreads();

    for (int o = t; o < XPR * 64; o += 256) {
        const int row = o >> 6, jj = o & 63;
        const float d = psum[row * 256 + jj] + psum[row * 256 + 64 + jj]
                      + psum[row * 256 + 128 + jj] + psum[row * 256 + 192 + jj];
        dbc[(size_t)(r0 + row) * 64 + jj] = d;
        if (jj < DTRANK) dlds[row * DTRANK + jj] = d;
    }
    __syncthreads();

#pragma unroll
    for (int rep = 0; rep < 4; ++rep) {
        const int e = rep * 256 + t;
        float4 wv[8];
        const float4* dtw4 = (const float4*)(dtw + (size_t)e * DTRANK);
#pragma unroll
        for (int q = 0; q < 8; ++q) wv[q] = dtw4[q];
        const float bias = dtb[e];
#pragma unroll
        for (int row = 0; row < XPR; ++row) {
            const float4* dl4 = (const float4*)(dlds + row * DTRANK);
            float sum = bias;
#pragma unroll
            for (int q = 0; q < 8; ++q) {
                const float4 dv = dl4[q];
                const float4 w = wv[q];
                sum += dv.x * w.x + dv.y * w.y + dv.z * w.z + dv.w * w.w;
            }
            delta[(size_t)(r0 + row) * DINNER + e] =
                fmaxf(sum, 0.f) + log1pf(__expf(-fabsf(sum)));
        }
    }
}

// ---------------------------------------------------------------------------
// Scan phase A: lane-per-channel, 16 states in registers.
// P[s] = exp2(Aes2[s] * sum(delta)); S = local scan end (h0=0).
// grid (DINNER/256, NB, NCHUNK)
// ---------------------------------------------------------------------------
__global__ __launch_bounds__(256) void scanA_kernel(
    const float* __restrict__ delta, const float* __restrict__ xc,
    const float* __restrict__ dbc, const float* __restrict__ A_log,
    float* __restrict__ chunkP, float* __restrict__ chunkS)
{
    const int tid = threadIdx.x;
    const int e = blockIdx.x * 256 + tid;
    const int b = blockIdx.y, ck = blockIdx.z;
    const int rbase = b * NL + ck * CH;

    float Aes2[DSTATE];
    const float4* al4 = (const float4*)(A_log + (size_t)e * DSTATE);
#pragma unroll
    for (int q = 0; q < 4; ++q) {
        const float4 a = al4[q];
        Aes2[q * 4 + 0] = -__expf(a.x) * LOG2E;
        Aes2[q * 4 + 1] = -__expf(a.y) * LOG2E;
        Aes2[q * 4 + 2] = -__expf(a.z) * LOG2E;
        Aes2[q * 4 + 3] = -__expf(a.w) * LOG2E;
    }

    float S[DSTATE];
#pragma unroll
    for (int s = 0; s < DSTATE; ++s) S[s] = 0.f;
    float cum = 0.f;
    const float* dp = delta + (size_t)rbase * DINNER + e;
    const float* xp = xc + (size_t)rbase * DINNER + e;
    for (int l = 0; l < CH; ++l) {
        const float dl = dp[(size_t)l * DINNER];
        const float xv = xp[(size_t)l * DINNER];
        const float* bu = dbc + (size_t)(rbase + l) * 64 + DTRANK;  // wave-uniform
        cum += dl;
        const float common = dl * xv;
#pragma unroll
        for (int s = 0; s < DSTATE; ++s) {
            const float dA = __builtin_amdgcn_exp2f(dl * Aes2[s]);
            S[s] = fmaf(dA, S[s], common * bu[s]);
        }
    }
    const size_t oi = (((size_t)b * NCHUNK + ck) * DINNER + e) * DSTATE;
    float4* Pp = (float4*)(chunkP + oi);
    float4* Sp = (float4*)(chunkS + oi);
#pragma unroll
    for (int q = 0; q < 4; ++q) {
        float4 pv, sv;
        pv.x = __builtin_amdgcn_exp2f(cum * Aes2[q * 4 + 0]);
        pv.y = __builtin_amdgcn_exp2f(cum * Aes2[q * 4 + 1]);
        pv.z = __builtin_amdgcn_exp2f(cum * Aes2[q * 4 + 2]);
        pv.w = __builtin_amdgcn_exp2f(cum * Aes2[q * 4 + 3]);
        sv.x = S[q * 4 + 0]; sv.y = S[q * 4 + 1];
        sv.z = S[q * 4 + 2]; sv.w = S[q * 4 + 3];
        Pp[q] = pv; Sp[q] = sv;
    }
}

// ---------------------------------------------------------------------------
// Phase B: serial scan over NCHUNK summaries; loads prefetched to registers.
// ---------------------------------------------------------------------------
__global__ __launch_bounds__(256) void scanB_kernel(
    const float* __restrict__ chunkP, float* __restrict__ chunkS)
{
    const int idx = blockIdx.x * 256 + threadIdx.x;    // 65536 threads
    const int b = idx >> 14;
    const int rem = idx & (DINNER * DSTATE - 1);
    const size_t base = (size_t)b * NCHUNK * (DINNER * DSTATE) + rem;
    float P[NCHUNK], S[NCHUNK];
#pragma unroll
    for (int c = 0; c < NCHUNK; ++c) {
        P[c] = chunkP[base + (size_t)c * (DINNER * DSTATE)];
        S[c] = chunkS[base + (size_t)c * (DINNER * DSTATE)];
    }
    float h = 0.f;
#pragma unroll
    for (int c = 0; c < NCHUNK; ++c) {
        chunkS[base + (size_t)c * (DINNER * DSTATE)] = h;   // h at chunk start
        h = fmaf(P[c], h, S[c]);
    }
}

// ---------------------------------------------------------------------------
// Phase C: lane-per-channel re-scan from h_init; gated y written as bf16.
// ---------------------------------------------------------------------------
__global__ __launch_bounds__(256) void scanC_kernel(
    const float* __restrict__ xz, const float* __restrict__ xc,
    const float* __restrict__ dbc, const float* __restrict__ A_log,
    const float* __restrict__ Dp, const float* __restrict__ hinit,
    const float* __restrict__ delta, unsigned short* __restrict__ yh)
{
    const int tid = threadIdx.x;
    const int e = blockIdx.x * 256 + tid;
    const int b = blockIdx.y, ck = blockIdx.z;
    const int rbase = b * NL + ck * CH;

    float Aes2[DSTATE];
    const float4* al4 = (const float4*)(A_log + (size_t)e * DSTATE);
#pragma unroll
    for (int q = 0; q < 4; ++q) {
        const float4 a = al4[q];
        Aes2[q * 4 + 0] = -__expf(a.x) * LOG2E;
        Aes2[q * 4 + 1] = -__expf(a.y) * LOG2E;
        Aes2[q * 4 + 2] = -__expf(a.z) * LOG2E;
        Aes2[q * 4 + 3] = -__expf(a.w) * LOG2E;
    }

    float h[DSTATE];
    const size_t oi = (((size_t)b * NCHUNK + ck) * DINNER + e) * DSTATE;
    const float4* h4 = (const float4*)(hinit + oi);
#pragma unroll
    for (int q = 0; q < 4; ++q) {
        const float4 v = h4[q];
        h[q * 4 + 0] = v.x; h[q * 4 + 1] = v.y; h[q * 4 + 2] = v.z; h[q * 4 + 3] = v.w;
    }
    const float Dv = Dp[e];

    const float* dp = delta + (size_t)rbase * DINNER + e;
    const float* xp = xc + (size_t)rbase * DINNER + e;
    const float* zp = xz + (size_t)rbase * (2 * DINNER) + DINNER + e;
    unsigned short* yp = yh + (size_t)rbase * DINNER + e;

    for (int l = 0; l < CH; ++l) {
        const float dl = dp[(size_t)l * DINNER];
        const float xv = xp[(size_t)l * DINNER];
        const float zv = zp[(size_t)l * 2 * DINNER];
        const float* bu = dbc + (size_t)(rbase + l) * 64 + DTRANK;  // wave-uniform
        const float common = dl * xv;
        float y = 0.f;
#pragma unroll
        for (int s = 0; s < DSTATE; ++s) {
            const float dA = __builtin_amdgcn_exp2f(dl * Aes2[s]);
            h[s] = fmaf(dA, h[s], common * bu[s]);
            y = fmaf(h[s], bu[DSTATE + s], y);
        }
        y = fmaf(Dv, xv, y);
        const float sig = __builtin_amdgcn_rcpf(1.f + __builtin_amdgcn_exp2f(-zv * LOG2E));
        yp[(size_t)l * DINNER] = f2bf(y * (zv * sig));
    }
}

// ---------------------------------------------------------------------------
extern "C" void kernel_launch(void* const* d_in, const int* in_sizes, int n_in,
                              void* d_out, int out_size, void* d_ws, size_t ws_size,
                              hipStream_t stream)
{
    const float* x          = (const float*)d_in[0];
    const float* in_proj_w  = (const float*)d_in[1];
    const float* conv_w     = (const float*)d_in[2];
    const float* conv_b     = (const float*)d_in[3];
    const float* x_proj_w   = (const float*)d_in[4];
    const float* dt_proj_w  = (const float*)d_in[5];
    const float* dt_proj_b  = (const float*)d_in[6];
    const float* A_log      = (const float*)d_in[7];
    const float* Dp         = (const float*)d_in[8];
    const float* out_proj_w = (const float*)d_in[9];
    float* out = (float*)d_out;

    float* ws  = (float*)d_ws;
    float* xz     = ws;                                  // 8,388,608 f
    float* xc     = xz + (size_t)NR * 2 * DINNER;        // 4,194,304 f
    float* dbc    = xc + (size_t)NR * DINNER;            //   262,144 f
    float* yb     = dbc + (size_t)NR * 64;               // 4,194,304 f (delta)
    float* chunkS = yb + (size_t)NR * DINNER;            // 2,097,152 f
    unsigned short* yh  = (unsigned short*)(chunkS + (size_t)NB * NCHUNK * DINNER * DSTATE);
    unsigned short* xh  = yh;                            // alias: dead before scanC writes yh
    unsigned short* wih = yh + (size_t)NR * DINNER;      // 1,048,576 ush
    unsigned short* woh = wih + (size_t)2 * DINNER * DMODEL;
    float* chunkP = out;   // exactly NB*NCHUNK*DINNER*DSTATE = out_size elems;
                           // fully rewritten by scanA, dead before final GEMM.

    // 0) casts to bf16
    cast_bf16_kernel<<<(NR * DMODEL / 4 + 255) / 256, 256, 0, stream>>>(x, xh, NR * DMODEL / 4);
    cast_bf16_kernel<<<(2 * DINNER * DMODEL / 4 + 255) / 256, 256, 0, stream>>>(
        in_proj_w, wih, 2 * DINNER * DMODEL / 4);
    cast_bf16_kernel<<<(DMODEL * DINNER / 4 + 255) / 256, 256, 0, stream>>>(
        out_proj_w, woh, DMODEL * DINNER / 4);

    // 1) xz = x @ in_proj_w^T  (bf16 MFMA)
    gemm_bf16_kernel<128><<<dim3(2 * DINNER / 128, NR / 128), 256, 0, stream>>>(
        xh, wih, xz, NR, 2 * DINNER, DMODEL);
    // 2) causal depthwise conv + SiLU
    conv_silu_kernel<<<NR * DINNER / 256, 256, 0, stream>>>(xz, conv_w, conv_b, xc);
    // 3+4) fused xproj + delta
    xpd_kernel<<<NR / XPR, 256, 0, stream>>>(xc, x_proj_w, dt_proj_w, dt_proj_b, dbc, yb);
    // 5) chunked parallel scan
    scanA_kernel<<<dim3(DINNER / 256, NB, NCHUNK), 256, 0, stream>>>(
        yb, xc, dbc, A_log, chunkP, chunkS);
    scanB_kernel<<<NB * DINNER * DSTATE / 256, 256, 0, stream>>>(chunkP, chunkS);
    scanC_kernel<<<dim3(DINNER / 256, NB, NCHUNK), 256, 0, stream>>>(
        xz, xc, dbc, A_log, Dp, chunkS, yb, yh);
    // 6) out = y @ out_proj_w^T  (bf16 MFMA)
    gemm_bf16_kernel<64><<<dim3(DMODEL / 64, NR / 128), 256, 0, stream>>>(
        yh, woh, out, NR, DMODEL, DINNER);
}